// Round 1
// baseline (444.020 us; speedup 1.0000x reference)
//
#include <hip/hip_runtime.h>

// CausalConv1d shift-register update, fp32.
// x:      (B=4096, H=4096)        f32
// state:  (B, H, K-1=3)           f32, k contiguous
// weight: (H, K=4)                f32
// bias:   (H,)                    f32
// out tuple flat: out (B*H) then new_state (B*H*3)
//
// One thread handles 4 consecutive h of one b:
//   state slice  = 12 contiguous floats (3x float4, 16B-aligned since group*48B)
//   x/out/bias   = 1x float4 each
//   new_state    = 3x float4 stores (register permutation of state + x)
//   weight       = 4x float4, L2-resident broadcast across batch

#ifndef CC_HIDDEN
#define CC_HIDDEN 4096
#endif
#ifndef CC_BATCH
#define CC_BATCH 4096
#endif

__global__ __launch_bounds__(256) void causal_conv1d_kernel(
    const float* __restrict__ x,        // B*H
    const float* __restrict__ state,    // B*H*3
    const float* __restrict__ weight,   // H*4
    const float* __restrict__ bias,     // H
    float* __restrict__ out,            // B*H
    float* __restrict__ new_state)      // B*H*3
{
    const long long g = (long long)blockIdx.x * blockDim.x + threadIdx.x; // one group = 4 h
    const long long ngroups = (long long)CC_BATCH * CC_HIDDEN / 4;
    if (g >= ngroups) return;

    const int hq = (int)(g % (CC_HIDDEN / 4));   // 4-h group index within the row
    const int h0 = hq * 4;
    const long long base = g * 4;                // flat index b*H + h0

    // ---- loads ----
    const float4 xv = *reinterpret_cast<const float4*>(x + base);
    const float4* sp = reinterpret_cast<const float4*>(state + base * 3);
    const float4 s0 = sp[0];   // f0  f1  f2  f3
    const float4 s1 = sp[1];   // f4  f5  f6  f7
    const float4 s2 = sp[2];   // f8  f9  f10 f11
    const float4* wp = reinterpret_cast<const float4*>(weight + (long long)h0 * 4);
    const float4 w0 = wp[0], w1 = wp[1], w2 = wp[2], w3 = wp[3];
    const float4 bv = *reinterpret_cast<const float4*>(bias + h0);

    // ---- out[j] = st0*w0 + st1*w1 + st2*w2 + x*w3 + bias ----
    // h0+0: (f0,f1,f2)   h0+1: (f3,f4,f5)   h0+2: (f6,f7,f8)   h0+3: (f9,f10,f11)
    float4 o;
    o.x = fmaf(s0.x, w0.x, fmaf(s0.y, w0.y, fmaf(s0.z, w0.z, fmaf(xv.x, w0.w, bv.x))));
    o.y = fmaf(s0.w, w1.x, fmaf(s1.x, w1.y, fmaf(s1.y, w1.z, fmaf(xv.y, w1.w, bv.y))));
    o.z = fmaf(s1.z, w2.x, fmaf(s1.w, w2.y, fmaf(s2.x, w2.z, fmaf(xv.z, w2.w, bv.z))));
    o.w = fmaf(s2.y, w3.x, fmaf(s2.z, w3.y, fmaf(s2.w, w3.z, fmaf(xv.w, w3.w, bv.w))));
    *reinterpret_cast<float4*>(out + base) = o;

    // ---- new_state = per-h (st1, st2, x) ----
    // flat: f1 f2 x0 | f4 f5 x1 | f7 f8 x2 | f10 f11 x3
    float4 n0, n1, n2;
    n0.x = s0.y; n0.y = s0.z; n0.z = xv.x; n0.w = s1.x;
    n1.x = s1.y; n1.y = xv.y; n1.z = s1.w; n1.w = s2.x;
    n2.x = xv.z; n2.y = s2.z; n2.z = s2.w; n2.w = xv.w;
    float4* np = reinterpret_cast<float4*>(new_state + base * 3);
    np[0] = n0; np[1] = n1; np[2] = n2;
}

extern "C" void kernel_launch(void* const* d_in, const int* in_sizes, int n_in,
                              void* d_out, int out_size, void* d_ws, size_t ws_size,
                              hipStream_t stream) {
    const float* x      = (const float*)d_in[0];
    const float* state  = (const float*)d_in[1];
    const float* weight = (const float*)d_in[2];
    const float* bias   = (const float*)d_in[3];

    const long long BH = (long long)CC_BATCH * CC_HIDDEN;
    float* out       = (float*)d_out;          // first B*H floats
    float* new_state = (float*)d_out + BH;     // next B*H*3 floats

    const long long ngroups = BH / 4;          // 4,194,304 threads
    const int block = 256;
    const int grid = (int)((ngroups + block - 1) / block);  // 16384 blocks

    causal_conv1d_kernel<<<grid, block, 0, stream>>>(x, state, weight, bias, out, new_state);
}

// Round 2
// 430.039 us; speedup vs baseline: 1.0325x; 1.0325x over previous
//
#include <hip/hip_runtime.h>

// CausalConv1d shift-register update, fp32 — round 2: LDS-transpose staging.
//
// x:      (B=4096, H=4096)  f32
// state:  (B, H, 3)         f32, k contiguous -> 48-byte records per 4-h group
// weight: (H, 4), bias: (H,)
// out tuple flat: out (B*H) then new_state (B*H*3)
//
// Round-1 issue: per-thread 3x float4 state loads/stores have a 48-B lane
// stride -> each global instruction spans 3 KB/wave at 1/3 utilization.
// Fix: stage the block's state chunk through LDS so every global load/store
// instruction is lane-contiguous (1 KB/wave), and do the 48-B-record
// redistribution in LDS (3 planes of 257 float4, +1 pad to break bank stride).
//
// Block = 256 threads, 4 h per thread -> 1024 flat elements per block.

#define CC_H 4096
#define CC_B 4096
#define BLOCK 256
#define EPB (BLOCK * 4)          // flat elements per block
#define PLANE 257                // 256 + 1 float4 pad per plane

__global__ __launch_bounds__(BLOCK) void causal_conv1d_kernel(
    const float* __restrict__ x,        // B*H
    const float* __restrict__ state,    // B*H*3
    const float* __restrict__ weight,   // H*4
    const float* __restrict__ bias,     // H
    float* __restrict__ out,            // B*H
    float* __restrict__ new_state)      // B*H*3
{
    __shared__ float4 lds[3 * PLANE];   // 12.3 KB

    const int tid = threadIdx.x;
    const long long base_e  = (long long)blockIdx.x * EPB;  // flat b*H+h base
    const long long base_x4 = base_e >> 2;                  // x/out in float4
    const long long base_s4 = (base_e * 3) >> 2;            // state in float4 (= blockIdx*768)

    const float4* stateF4 = reinterpret_cast<const float4*>(state);
    const float4* xF4     = reinterpret_cast<const float4*>(x);

    // ---- stage state: contiguous global -> transposed LDS planes ----
    // block-local float4 j belongs to thread t = j/3, slot s = j%3
    #pragma unroll
    for (int i = 0; i < 3; ++i) {
        const int j = i * BLOCK + tid;          // 0..767
        const int t = j / 3;
        const int s = j - t * 3;
        lds[s * PLANE + t] = stateF4[base_s4 + j];
    }

    // ---- weight/bias/x (contiguous or L2-resident) while LDS fills ----
    const int h0 = (int)(base_e & (CC_H - 1)) + tid * 4;
    const float4* wp = reinterpret_cast<const float4*>(weight + (long long)h0 * 4);
    const float4 w0 = wp[0], w1 = wp[1], w2 = wp[2], w3 = wp[3];
    const float4 bv = *reinterpret_cast<const float4*>(bias + h0);
    const float4 xv = xF4[base_x4 + tid];

    __syncthreads();

    const float4 s0 = lds[0 * PLANE + tid];   // f0  f1  f2  f3
    const float4 s1 = lds[1 * PLANE + tid];   // f4  f5  f6  f7
    const float4 s2 = lds[2 * PLANE + tid];   // f8  f9  f10 f11

    // ---- out[j] = st0*w0 + st1*w1 + st2*w2 + x*w3 + bias ----
    float4 o;
    o.x = fmaf(s0.x, w0.x, fmaf(s0.y, w0.y, fmaf(s0.z, w0.z, fmaf(xv.x, w0.w, bv.x))));
    o.y = fmaf(s0.w, w1.x, fmaf(s1.x, w1.y, fmaf(s1.y, w1.z, fmaf(xv.y, w1.w, bv.y))));
    o.z = fmaf(s1.z, w2.x, fmaf(s1.w, w2.y, fmaf(s2.x, w2.z, fmaf(xv.z, w2.w, bv.z))));
    o.w = fmaf(s2.y, w3.x, fmaf(s2.z, w3.y, fmaf(s2.w, w3.z, fmaf(xv.w, w3.w, bv.w))));
    reinterpret_cast<float4*>(out)[base_x4 + tid] = o;

    // ---- new_state permutation: f1 f2 x0 | f4 f5 x1 | f7 f8 x2 | f10 f11 x3 ----
    float4 n0, n1, n2;
    n0.x = s0.y; n0.y = s0.z; n0.z = xv.x; n0.w = s1.x;
    n1.x = s1.y; n1.y = xv.y; n1.z = s1.w; n1.w = s2.x;
    n2.x = xv.z; n2.y = s2.z; n2.z = s2.w; n2.w = xv.w;

    // thread t writes exactly the plane slots it just read -> no barrier needed here
    lds[0 * PLANE + tid] = n0;
    lds[1 * PLANE + tid] = n1;
    lds[2 * PLANE + tid] = n2;

    __syncthreads();

    // ---- drain: transposed LDS planes -> contiguous global ----
    float4* nsF4 = reinterpret_cast<float4*>(new_state);
    #pragma unroll
    for (int i = 0; i < 3; ++i) {
        const int j = i * BLOCK + tid;
        const int t = j / 3;
        const int s = j - t * 3;
        nsF4[base_s4 + j] = lds[s * PLANE + t];
    }
}

extern "C" void kernel_launch(void* const* d_in, const int* in_sizes, int n_in,
                              void* d_out, int out_size, void* d_ws, size_t ws_size,
                              hipStream_t stream) {
    const float* x      = (const float*)d_in[0];
    const float* state  = (const float*)d_in[1];
    const float* weight = (const float*)d_in[2];
    const float* bias   = (const float*)d_in[3];

    const long long BH = (long long)CC_B * CC_H;
    float* out       = (float*)d_out;          // first B*H floats
    float* new_state = (float*)d_out + BH;     // next B*H*3 floats

    const int grid = (int)(BH / EPB);          // 16384 blocks
    causal_conv1d_kernel<<<grid, BLOCK, 0, stream>>>(x, state, weight, bias, out, new_state);
}

// Round 4
// 422.090 us; speedup vs baseline: 1.0520x; 1.0188x over previous
//
#include <hip/hip_runtime.h>

// CausalConv1d shift-register update, fp32 — round 4: nontemporal streaming
// (round-3 compile fix: __builtin_nontemporal_* rejects HIP_vector_type;
//  use native clang ext_vector_type(4) float vectors instead).
//
// Theory: the harness's 1.3 GiB 0xAA poison fills leave L2/L3 fully dirty
// before every replay; our 256 MB of read allocations force dirty writebacks
// (~+250 MB phantom HBM traffic). Fix: `nt` (no-allocate) loads for x/state
// and `nt` stores for out/new_state — zero-reuse streams never claim cache
// lines. weight/bias (80 KB, reused 4096x) stay normally cached.
//
// Structure: block=256 threads, 4 h/thread, state records redistributed
// through padded LDS planes so every global instruction is lane-contiguous.

#define CC_H 4096
#define CC_B 4096
#define BLOCK 256
#define EPB (BLOCK * 4)          // flat elements per block
#define PLANE 257                // 256 + 1 vector pad per plane

typedef float f32x4 __attribute__((ext_vector_type(4)));

__global__ __launch_bounds__(BLOCK) void causal_conv1d_kernel(
    const float* __restrict__ x,        // B*H
    const float* __restrict__ state,    // B*H*3
    const float* __restrict__ weight,   // H*4
    const float* __restrict__ bias,     // H
    float* __restrict__ out,            // B*H
    float* __restrict__ new_state)      // B*H*3
{
    __shared__ f32x4 lds[3 * PLANE];    // 12.3 KB

    const int tid = threadIdx.x;
    const long long base_e  = (long long)blockIdx.x * EPB;  // flat b*H+h base
    const long long base_x4 = base_e >> 2;                  // x/out in vec4
    const long long base_s4 = (base_e * 3) >> 2;            // state in vec4

    const f32x4* stateV = reinterpret_cast<const f32x4*>(state);
    const f32x4* xV     = reinterpret_cast<const f32x4*>(x);

    // ---- stage state: contiguous global (nt) -> transposed LDS planes ----
    #pragma unroll
    for (int i = 0; i < 3; ++i) {
        const int j = i * BLOCK + tid;          // 0..767
        const int t = j / 3;
        const int s = j - t * 3;
        lds[s * PLANE + t] = __builtin_nontemporal_load(&stateV[base_s4 + j]);
    }

    // ---- weight/bias (cached, L2-resident) and x (nt) ----
    const int h0 = (int)(base_e & (CC_H - 1)) + tid * 4;
    const f32x4* wp = reinterpret_cast<const f32x4*>(weight + (long long)h0 * 4);
    const f32x4 w0 = wp[0], w1 = wp[1], w2 = wp[2], w3 = wp[3];
    const f32x4 bv = *reinterpret_cast<const f32x4*>(bias + h0);
    const f32x4 xv = __builtin_nontemporal_load(&xV[base_x4 + tid]);

    __syncthreads();

    const f32x4 s0 = lds[0 * PLANE + tid];   // f0  f1  f2  f3
    const f32x4 s1 = lds[1 * PLANE + tid];   // f4  f5  f6  f7
    const f32x4 s2 = lds[2 * PLANE + tid];   // f8  f9  f10 f11

    // ---- out[j] = st0*w0 + st1*w1 + st2*w2 + x*w3 + bias ----
    f32x4 o;
    o.x = fmaf(s0.x, w0.x, fmaf(s0.y, w0.y, fmaf(s0.z, w0.z, fmaf(xv.x, w0.w, bv.x))));
    o.y = fmaf(s0.w, w1.x, fmaf(s1.x, w1.y, fmaf(s1.y, w1.z, fmaf(xv.y, w1.w, bv.y))));
    o.z = fmaf(s1.z, w2.x, fmaf(s1.w, w2.y, fmaf(s2.x, w2.z, fmaf(xv.z, w2.w, bv.z))));
    o.w = fmaf(s2.y, w3.x, fmaf(s2.z, w3.y, fmaf(s2.w, w3.z, fmaf(xv.w, w3.w, bv.w))));
    __builtin_nontemporal_store(o, &reinterpret_cast<f32x4*>(out)[base_x4 + tid]);

    // ---- new_state permutation: f1 f2 x0 | f4 f5 x1 | f7 f8 x2 | f10 f11 x3 ----
    f32x4 n0, n1, n2;
    n0.x = s0.y; n0.y = s0.z; n0.z = xv.x; n0.w = s1.x;
    n1.x = s1.y; n1.y = xv.y; n1.z = s1.w; n1.w = s2.x;
    n2.x = xv.z; n2.y = s2.z; n2.z = s2.w; n2.w = xv.w;

    // thread t writes exactly the plane slots it just read -> no barrier needed
    lds[0 * PLANE + tid] = n0;
    lds[1 * PLANE + tid] = n1;
    lds[2 * PLANE + tid] = n2;

    __syncthreads();

    // ---- drain: transposed LDS planes -> contiguous global (nt) ----
    f32x4* nsV = reinterpret_cast<f32x4*>(new_state);
    #pragma unroll
    for (int i = 0; i < 3; ++i) {
        const int j = i * BLOCK + tid;
        const int t = j / 3;
        const int s = j - t * 3;
        __builtin_nontemporal_store(lds[s * PLANE + t], &nsV[base_s4 + j]);
    }
}

extern "C" void kernel_launch(void* const* d_in, const int* in_sizes, int n_in,
                              void* d_out, int out_size, void* d_ws, size_t ws_size,
                              hipStream_t stream) {
    const float* x      = (const float*)d_in[0];
    const float* state  = (const float*)d_in[1];
    const float* weight = (const float*)d_in[2];
    const float* bias   = (const float*)d_in[3];

    const long long BH = (long long)CC_B * CC_H;
    float* out       = (float*)d_out;          // first B*H floats
    float* new_state = (float*)d_out + BH;     // next B*H*3 floats

    const int grid = (int)(BH / EPB);          // 16384 blocks
    causal_conv1d_kernel<<<grid, BLOCK, 0, stream>>>(x, state, weight, bias, out, new_state);
}